// Round 9
// baseline (294.214 us; speedup 1.0000x reference)
//
#include <hip/hip_runtime.h>

// Correlation / cost volume:
// corr[n, dy*9+dx, h, w] = sum_c f0[n,c,h,w] * f1[n,c,h+dy-4,w+dx-4] (0-padded)
// N=8, C=256, H=W=128 -> D=9, 81 disp channels.
//
// R8 post-mortem: VALUBusy 26%, Occ 5.4 waves/CU, conflicts 1.4e7 -> the
// 3-wave __syncthreads (vmcnt(0)+lgkmcnt(0) drain, m97 pathology) stalls all
// waves every chunk. R9: BARRIER-FREE.
//  - Each wave owns a PRIVATE LDS slice; no __syncthreads anywhere.
//    Same-wave ds_write -> ds_read ordering: per-wave in-order LDS pipe +
//    asm lgkmcnt(0) compiler fence after staging.
//  - Wave tile: 2 h-rows x 128 w x 1 dy. lane: row=lane>>5, quad q=lane&31.
//    acc = 9 x float4 = 36 VGPR. CCH=2 -> 128 chunks.
//  - Staging is EXACTLY linear: lane l writes LDS 16B-unit l (68 units =
//    2 rows x 34; lanes 0..3 write units 64..67 too). Reads: units
//    row*34 + q + {0,1,2} -> every 8-lane phase = 8 consecutive units.
//  - 3 waves/block (j = dy%3) read IDENTICAL f0 addresses -> L1 dedup;
//    dyg innermost in grid -> f1-row overlap L1/L2-local. XCD: image = XCD.
//  - grid 1536 = 6 blocks/CU, ~18 waves/CU, VGPR ~110 -> 4-5 waves/SIMD.

#define DD    9
#define Hh    128
#define Ww    128
#define Cc    256
#define WROW  136        // floats per staged row (pad4 + 128 + pad4)
#define CHF   272        // floats per channel (2 rows)
#define BUFQ  544        // floats per buffer (2 channels)
#define WAVEF 1088       // floats per wave (double buffer)
#define NCH   128        // chunks of 2 channels

__global__ __launch_bounds__(192) __attribute__((amdgpu_waves_per_eu(2, 8)))
void corr_kernel(const float* __restrict__ f0,
                 const float* __restrict__ f1,
                 float* __restrict__ out) {
    const int tid  = threadIdx.x;
    const int j    = tid >> 6;         // wave id: dy = dyg*3 + j
    const int lane = tid & 63;
    const int row  = lane >> 5;        // 0..1 (h-row within pair)
    const int q    = lane & 31;        // w-quad 0..31

    const int bid = blockIdx.x;
    const int n   = bid & 7;           // XCD swizzle: image per XCD
    const int rem = bid >> 3;          // 0..191
    const int hp  = rem / 3;           // h-pair 0..63
    const int dyg = rem % 3;           // dyg innermost: f1-row reuse in time
    const int dy  = dyg * 3 + j;
    const int h0  = hp * 2;

    __shared__ float lds[3 * WAVEF];   // 13056 B, one slice per wave
    float* const wlds = lds + j * WAVEF;

    const size_t plane = (size_t)Hh * Ww;
    const float* f0p = f0 + ((size_t)n * Cc) * plane + (size_t)(h0 + row) * Ww + 4 * q;
    const float* f1n = f1 + ((size_t)n * Cc) * plane;

    // ---- staging map: 68 quads = 2 rows x 34 units; unit(lane l) = l
    const int rq0 = (lane < 34) ? 0 : 1;
    const int uq0 = lane - 34 * rq0;
    const bool has1 = (lane < 4);
    const int uq1 = 30 + lane;                 // row 1 units 30..33 (lane<4)

    const int ghA = h0 + dy - 4 + rq0;
    const int ghB = h0 + dy - 3;               // row 1
    const bool ok0 = (uq0 >= 1) && (uq0 <= 32) && ((unsigned)ghA < (unsigned)Hh);
    const bool ok1 = has1 && (uq1 <= 32) && ((unsigned)ghB < (unsigned)Hh);
    const float* sp0 = f1n + (size_t)ghA * Ww + (4 * uq0 - 4);
    const float* sp1 = f1n + (size_t)ghB * Ww + (4 * uq1 - 4);
    const int lo0 = rq0 * WROW + 4 * uq0;
    const int lo1 = WROW + 4 * uq1;

    // ---- read geometry
    const int rb = row * WROW + 4 * q;

    const float4 zero4 = make_float4(0.f, 0.f, 0.f, 0.f);

    float4 acc[DD];
#pragma unroll
    for (int d = 0; d < DD; ++d) acc[d] = zero4;

    float4 s0a, s0b, s1a, s1b;     // f1 staging (2 channels x up to 2 quads)
    float4 a0, a1;                 // f0 current chunk
    float4 m0, m1;                 // f0 next chunk

#define LOADF1(K)                                                        \
    {                                                                    \
        const size_t cofs = (size_t)(2 * (K)) * plane;                   \
        s0a = ok0 ? *(const float4*)(sp0 + cofs)         : zero4;        \
        s0b = ok0 ? *(const float4*)(sp0 + cofs + plane) : zero4;        \
        s1a = ok1 ? *(const float4*)(sp1 + cofs)         : zero4;        \
        s1b = ok1 ? *(const float4*)(sp1 + cofs + plane) : zero4;        \
    }

#define LOADF0(K, d0, d1)                                                \
    {                                                                    \
        const float* p = f0p + (size_t)(2 * (K)) * plane;                \
        d0 = *(const float4*)(p);                                        \
        d1 = *(const float4*)(p + plane);                                \
    }

#define STOREF1(B)                                                       \
    {                                                                    \
        float* base = wlds + (B) * BUFQ;                                 \
        *(float4*)(base + lo0)       = s0a;                              \
        *(float4*)(base + CHF + lo0) = s0b;                              \
        if (has1) {                                                      \
            *(float4*)(base + lo1)       = s1a;                          \
            *(float4*)(base + CHF + lo1) = s1b;                          \
        }                                                                \
        asm volatile("s_waitcnt lgkmcnt(0)" ::: "memory");               \
    }

#define COMP1(B, CC, A)                                                  \
    {                                                                    \
        const float* lrow = wlds + (B) * BUFQ + (CC) * CHF + rb;         \
        const float4 v0 = *(const float4*)(lrow);                        \
        const float4 v1 = *(const float4*)(lrow + 4);                    \
        const float4 v2 = *(const float4*)(lrow + 8);                    \
        const float w[12] = {v0.x, v0.y, v0.z, v0.w,                     \
                             v1.x, v1.y, v1.z, v1.w,                     \
                             v2.x, v2.y, v2.z, v2.w};                    \
        _Pragma("unroll")                                                \
        for (int dx = 0; dx < DD; ++dx) {                                \
            acc[dx].x += (A).x * w[dx + 0];                              \
            acc[dx].y += (A).y * w[dx + 1];                              \
            acc[dx].z += (A).z * w[dx + 2];                              \
            acc[dx].w += (A).w * w[dx + 3];                              \
        }                                                                \
    }

    LOADF1(0);
    LOADF0(0, a0, a1);
    STOREF1(0);

#pragma unroll 2
    for (int k = 0; k < NCH; ++k) {
        const int b = k & 1;
        if (k + 1 < NCH) {
            LOADF1(k + 1);
            LOADF0(k + 1, m0, m1);
        }
        COMP1(b, 0, a0);
        COMP1(b, 1, a1);
        if (k + 1 < NCH) {
            STOREF1(b ^ 1);        // own buffer; fence orders write->next read
            a0 = m0; a1 = m1;
        }
    }

    // ---- epilogue: 9 quad stores (each 32-lane half coalesced per dx)
    float* outp = out + ((size_t)n * (DD * DD) + (size_t)dy * DD) * plane
                      + (size_t)(h0 + row) * Ww + 4 * q;
#pragma unroll
    for (int dx = 0; dx < DD; ++dx)
        *(float4*)(outp + (size_t)dx * plane) = acc[dx];
}

extern "C" void kernel_launch(void* const* d_in, const int* in_sizes, int n_in,
                              void* d_out, int out_size, void* d_ws, size_t ws_size,
                              hipStream_t stream) {
    const float* f0 = (const float*)d_in[0];
    const float* f1 = (const float*)d_in[1];
    float* out = (float*)d_out;
    // grid: 8 n * 64 h-pairs * 3 dyg = 1536 blocks, 192 threads (3 indep waves)
    corr_kernel<<<dim3(1536), dim3(192), 0, stream>>>(f0, f1, out);
}

// Round 10
// 180.423 us; speedup vs baseline: 1.6307x; 1.6307x over previous
//
#include <hip/hip_runtime.h>

// Correlation / cost volume:
// corr[n, dy*9+dx, h, w] = sum_c f0[n,c,h,w] * f1[n,c,h+dy-4,w+dx-4] (0-padded)
// N=8, C=256, H=W=128 -> D=9, 81 disp channels.
//
// R4-R9 lesson: every LDS-staged variant stalls at 20-28% VALUBusy -- the
// global->reg->LDS round-trip adds a serial vmcnt dependency per chunk, an
// LDS-pipe floor (~72us), and staging VALU, while the window overlap it
// dedups is tiny (~1KB/chunk/wave) and L1 serves it directly.
// R10: NO LDS, NO barriers. Direct global loads of the shifted windows.
//  - thread: 4 px x 9 dx x 1 dy. acc = 9 float4 = 36 VGPR.
//  - wave = 2 h-rows x 32 quads; block = 3 waves (dy = dyg*3 + j), waves
//    fully independent; 3 waves share identical f0 addresses (L1 dedup),
//    f1 rows overlap across j/dyg (L1/L2).
//  - per chunk: 1 f0 quad + 3 f1 quads (all 16B-aligned; window is
//    cols wq-4..wq+7). Edges: clamped invariant offsets + cndmask zeroing
//    (f0 quad by rowok; left quad q==0; right quad q==31).
//  - 4-slot register ring, prefetch 3 chunks ahead (~260cy cover), ~12
//    outstanding loads/wave MLP. Uniform chunk pointers advance on SALU.
//  - grid 1536 = 8n x 64hp x 3dyg, XCD-swizzled (n = bid&7 = XCD).

#define DD    9
#define Hh    128
#define Ww    128
#define Cc    256
#define PLANE 16384

__global__ __launch_bounds__(192) __attribute__((amdgpu_waves_per_eu(2, 8)))
void corr_kernel(const float* __restrict__ f0,
                 const float* __restrict__ f1,
                 float* __restrict__ out) {
    const int tid  = threadIdx.x;
    const int j    = tid >> 6;         // wave: dy = dyg*3 + j
    const int lane = tid & 63;
    const int row  = lane >> 5;        // 0..1
    const int q    = lane & 31;        // w-quad

    const int bid = blockIdx.x;
    const int n   = bid & 7;           // XCD swizzle: image per XCD
    const int rem = bid >> 3;
    const int hp  = rem / 3;           // 0..63
    const int dyg = rem % 3;           // innermost: f1-row reuse in time
    const int dy  = dyg * 3 + j;
    const int h   = hp * 2 + row;

    const int wq = 4 * q;
    const int gh = h + dy - 4;
    const bool rowok = ((unsigned)gh < (unsigned)Hh);
    const bool okL   = (q >= 1);
    const bool okR   = (q <= 30);

    // invariant lane offsets (floats); clamped so every address is in-bounds
    const int f0off = h * Ww + wq;
    const int f1mid = (rowok ? gh : 0) * Ww + wq;
    const int f1lo  = okL ? (f1mid - 4) : f1mid;
    const int f1hi  = okR ? (f1mid + 4) : f1mid;

    const float* p0 = f0 + (size_t)n * Cc * PLANE;   // uniform chunk ptrs
    const float* p1 = f1 + (size_t)n * Cc * PLANE;

    const float4 z4 = make_float4(0.f, 0.f, 0.f, 0.f);

    float4 acc[DD];
#pragma unroll
    for (int d = 0; d < DD; ++d) acc[d] = z4;

    // 4-slot ring: f0 quad a*, f1 quads l*/m*/r*
    float4 a0, l0, m0, r0, a1, l1, m1, r1;
    float4 a2, l2, m2, r2, a3, l3, m3, r3;

#define LOADS(S)                                                         \
    {                                                                    \
        a##S = *(const float4*)(p0 + f0off);                             \
        l##S = *(const float4*)(p1 + f1lo);                              \
        m##S = *(const float4*)(p1 + f1mid);                             \
        r##S = *(const float4*)(p1 + f1hi);                              \
        p0 += PLANE; p1 += PLANE;                                        \
    }

#define COMPS(S)                                                         \
    {                                                                    \
        const float4 av = rowok ? a##S : z4;                             \
        const float4 lv = okL   ? l##S : z4;                             \
        const float4 rv = okR   ? r##S : z4;                             \
        const float w[12] = {lv.x, lv.y, lv.z, lv.w,                     \
                             m##S.x, m##S.y, m##S.z, m##S.w,             \
                             rv.x, rv.y, rv.z, rv.w};                    \
        _Pragma("unroll")                                                \
        for (int dx = 0; dx < DD; ++dx) {                                \
            acc[dx].x += av.x * w[dx + 0];                               \
            acc[dx].y += av.y * w[dx + 1];                               \
            acc[dx].z += av.z * w[dx + 2];                               \
            acc[dx].w += av.w * w[dx + 3];                               \
        }                                                                \
    }

    LOADS(0);           // chunk 0
    LOADS(1);           // chunk 1
    LOADS(2);           // chunk 2

    for (int i = 0; i < 252; i += 4) {
        LOADS(3); COMPS(0);        // load i+3, compute i
        LOADS(0); COMPS(1);        // load i+4, compute i+1
        LOADS(1); COMPS(2);
        LOADS(2); COMPS(3);
    }
    LOADS(3);                       // chunk 255
    COMPS(0); COMPS(1); COMPS(2); COMPS(3);   // chunks 252..255

    // epilogue: 9 quad stores
    float* outp = out + ((size_t)n * (DD * DD) + (size_t)dy * DD) * PLANE
                      + (size_t)h * Ww + wq;
#pragma unroll
    for (int dx = 0; dx < DD; ++dx)
        *(float4*)(outp + (size_t)dx * PLANE) = acc[dx];
}

extern "C" void kernel_launch(void* const* d_in, const int* in_sizes, int n_in,
                              void* d_out, int out_size, void* d_ws, size_t ws_size,
                              hipStream_t stream) {
    const float* f0 = (const float*)d_in[0];
    const float* f1 = (const float*)d_in[1];
    float* out = (float*)d_out;
    // grid: 8 n * 64 h-pairs * 3 dyg = 1536 blocks, 192 threads (3 indep waves)
    corr_kernel<<<dim3(1536), dim3(192), 0, stream>>>(f0, f1, out);
}